// Round 1
// baseline (858.457 us; speedup 1.0000x reference)
//
#include <hip/hip_runtime.h>
#include <hip/hip_bf16.h>

// Problem constants
#define BB 4
#define LL 2048
#define SS 2048
#define EE 1024
#define HH 16
#define DD 64
#define MM (BB * LL)   // 8192 rows for all projections

typedef unsigned short u16;
typedef u16   u16x4  __attribute__((ext_vector_type(4)));
typedef u16   u16x8  __attribute__((ext_vector_type(8)));
typedef float f32x4  __attribute__((ext_vector_type(4)));
typedef __bf16 bf16x8 __attribute__((ext_vector_type(8)));

__device__ __forceinline__ u16 f2bf(float x) {
    unsigned u = __float_as_uint(x);
    u += 0x7fffu + ((u >> 16) & 1u);       // RNE (inputs finite)
    return (u16)(u >> 16);
}
__device__ __forceinline__ float bf2f(u16 b) {
    return __uint_as_float(((unsigned)b) << 16);
}

// ---------------------------------------------------------------------------
// comb[l][s] = bf16(attn_bias[l][s] + attn_mask[l][s])
__global__ __launch_bounds__(256) void combine_bias_kernel(
    const float* __restrict__ bias, const float* __restrict__ mask,
    u16* __restrict__ comb)
{
    int idx = (blockIdx.x * 256 + threadIdx.x) * 8;
    f32x4 a0 = *(const f32x4*)(bias + idx);
    f32x4 a1 = *(const f32x4*)(bias + idx + 4);
    f32x4 m0 = *(const f32x4*)(mask + idx);
    f32x4 m1 = *(const f32x4*)(mask + idx + 4);
    u16x8 o;
#pragma unroll
    for (int j = 0; j < 4; j++) { o[j] = f2bf(a0[j] + m0[j]); o[4 + j] = f2bf(a1[j] + m1[j]); }
    *(u16x8*)(comb + idx) = o;
}

// ---------------------------------------------------------------------------
// C[m][n] = (sum_k A[m][k]*Bw[n][k] + bias[n]) * scale
// A: [M,K] fp32 (ABF16=0) or bf16 (ABF16=1); Bw: [N,K] fp32; C bf16/fp32.
// 128x128 tile, BK=64, 256 threads (4 waves 2x2), mfma_f32_16x16x32_bf16.
template <int ABF16, int OUTBF16>
__global__ __launch_bounds__(256) void gemm_bt(
    const void* __restrict__ Ap, const float* __restrict__ Bw,
    const float* __restrict__ bias, void* __restrict__ Cp,
    int M, int N, int K, float scale)
{
    __shared__ __align__(16) u16 As[128 * 72];
    __shared__ __align__(16) u16 Bs[128 * 72];
    const int tid = threadIdx.x;
    const int lane = tid & 63, wave = tid >> 6;
    const int quad = lane >> 4, ln = lane & 15;
    const int wm = (wave & 1) * 64, wn = (wave >> 1) * 64;
    const int m0 = blockIdx.x * 128, n0 = blockIdx.y * 128;

    f32x4 acc[4][4];
#pragma unroll
    for (int mt = 0; mt < 4; mt++)
#pragma unroll
        for (int nt = 0; nt < 4; nt++) acc[mt][nt] = (f32x4){0.f, 0.f, 0.f, 0.f};

    const float* Af = (const float*)Ap;
    const u16*   Ab = (const u16*)Ap;

    for (int k0 = 0; k0 < K; k0 += 64) {
        __syncthreads();
        if (ABF16) {
#pragma unroll
            for (int i = 0; i < 4; i++) {             // 1024 chunks of 8 bf16
                int chunk = tid + 256 * i;
                int row = chunk >> 3, c = chunk & 7;
                u16x8 v = *(const u16x8*)(Ab + (m0 + row) * K + k0 + c * 8);
                *(u16x8*)(As + row * 72 + c * 8) = v;
            }
        } else {
#pragma unroll
            for (int i = 0; i < 8; i++) {             // 2048 chunks of 4 fp32
                int chunk = tid + 256 * i;
                int row = chunk >> 4, c = chunk & 15;
                f32x4 v = *(const f32x4*)(Af + (m0 + row) * K + k0 + c * 4);
                u16x4 o;
#pragma unroll
                for (int j = 0; j < 4; j++) o[j] = f2bf(v[j]);
                *(u16x4*)(As + row * 72 + c * 4) = o;
            }
        }
#pragma unroll
        for (int i = 0; i < 8; i++) {                 // B always fp32
            int chunk = tid + 256 * i;
            int row = chunk >> 4, c = chunk & 15;
            f32x4 v = *(const f32x4*)(Bw + (n0 + row) * K + k0 + c * 4);
            u16x4 o;
#pragma unroll
            for (int j = 0; j < 4; j++) o[j] = f2bf(v[j]);
            *(u16x4*)(Bs + row * 72 + c * 4) = o;
        }
        __syncthreads();

#pragma unroll
        for (int ks = 0; ks < 2; ks++) {
            bf16x8 af[4], bfg[4];
#pragma unroll
            for (int mt = 0; mt < 4; mt++)
                af[mt] = *(const bf16x8*)(As + (wm + mt * 16 + ln) * 72 + ks * 32 + quad * 8);
#pragma unroll
            for (int nt = 0; nt < 4; nt++)
                bfg[nt] = *(const bf16x8*)(Bs + (wn + nt * 16 + ln) * 72 + ks * 32 + quad * 8);
#pragma unroll
            for (int mt = 0; mt < 4; mt++)
#pragma unroll
                for (int nt = 0; nt < 4; nt++)
                    acc[mt][nt] = __builtin_amdgcn_mfma_f32_16x16x32_bf16(
                        af[mt], bfg[nt], acc[mt][nt], 0, 0, 0);
        }
    }

#pragma unroll
    for (int nt = 0; nt < 4; nt++) {
        int n = n0 + wn + nt * 16 + ln;
        float bn = bias[n];
#pragma unroll
        for (int mt = 0; mt < 4; mt++) {
#pragma unroll
            for (int r = 0; r < 4; r++) {
                int m = m0 + wm + mt * 16 + quad * 4 + r;
                float val = (acc[mt][nt][r] + bn) * scale;
                if (OUTBF16) ((u16*)Cp)[m * N + n] = f2bf(val);
                else         ((float*)Cp)[m * N + n] = val;
            }
        }
    }
}

// ---------------------------------------------------------------------------
// vt[b][h][d][s] = v_bf[b][s][h*64+d]
__global__ __launch_bounds__(256) void transpose_v_kernel(
    const u16* __restrict__ vb, u16* __restrict__ vt)
{
    __shared__ __align__(16) u16 t[64 * 72];
    const int bh = blockIdx.y, b = bh >> 4, h = bh & 15;
    const int s0 = blockIdx.x * 64;
    const int tid = threadIdx.x;
#pragma unroll
    for (int i = 0; i < 2; i++) {
        int chunk = tid + 256 * i;                    // 512 = 64 rows x 8
        int row = chunk >> 3, c = chunk & 7;
        u16x8 v = *(const u16x8*)(vb + (b * SS + s0 + row) * EE + h * 64 + c * 8);
        *(u16x8*)(t + row * 72 + c * 8) = v;
    }
    __syncthreads();
#pragma unroll
    for (int i = 0; i < 2; i++) {
        int chunk = tid + 256 * i;
        int d = chunk >> 3, c = chunk & 7;
        u16x8 o;
#pragma unroll
        for (int j = 0; j < 8; j++) o[j] = t[(c * 8 + j) * 72 + d];
        *(u16x8*)(vt + (bh * 64 + d) * SS + s0 + c * 8) = o;
    }
}

// ---------------------------------------------------------------------------
// Attention: per block 64 q-rows of one (b,h); S^T = K*Q^T formulation.
// No max-subtraction softmax (scores bounded ~|10|); O^T = V^T * P.
__global__ __launch_bounds__(256) void attn_kernel(
    const u16* __restrict__ qb,   // [B,L,E] bf16, pre-scaled
    const u16* __restrict__ kb,   // [B,S,E] bf16
    const u16* __restrict__ vt,   // [B*H,64,S] bf16
    const u16* __restrict__ comb, // [L,S] bf16 (mask+bias)
    u16* __restrict__ attn)       // [B,L,E] bf16
{
    __shared__ __align__(16) u16 Ks[128 * 72];    // K tile [s][d]
    __shared__ __align__(16) u16 Vs[64 * 136];    // V^T tile [d][s]
    __shared__ __align__(16) u16 Ps[64 * 136];    // bias tile then P^T [q][s]
    const int tid = threadIdx.x, lane = tid & 63, wave = tid >> 6;
    const int quad = lane >> 4, ln = lane & 15;
    const int bh = blockIdx.y, b = bh >> 4, h = bh & 15;
    const int q0 = blockIdx.x * 64;
    const int qrow = q0 + wave * 16 + ln;         // this lane's q column

    bf16x8 qf[2];
#pragma unroll
    for (int ks = 0; ks < 2; ks++)
        qf[ks] = *(const bf16x8*)(qb + (b * LL + qrow) * EE + h * 64 + ks * 32 + quad * 8);

    f32x4 o[4];
#pragma unroll
    for (int mt = 0; mt < 4; mt++) o[mt] = (f32x4){0.f, 0.f, 0.f, 0.f};
    float lsum = 0.f;

    for (int s0 = 0; s0 < SS; s0 += 128) {
        __syncthreads();                           // prev-iter LDS reads done
#pragma unroll
        for (int i = 0; i < 4; i++) {              // K: 128 rows x 8 chunks
            int chunk = tid + 256 * i;
            int row = chunk >> 3, c = chunk & 7;
            *(u16x8*)(Ks + row * 72 + c * 8) =
                *(const u16x8*)(kb + (b * SS + s0 + row) * EE + h * 64 + c * 8);
        }
#pragma unroll
        for (int i = 0; i < 4; i++) {              // V^T: 64 rows x 16 chunks
            int chunk = tid + 256 * i;
            int row = chunk >> 4, c = chunk & 15;
            *(u16x8*)(Vs + row * 136 + c * 8) =
                *(const u16x8*)(vt + (bh * 64 + row) * SS + s0 + c * 8);
        }
#pragma unroll
        for (int i = 0; i < 4; i++) {              // bias tile: 64 l x 16 chunks
            int chunk = tid + 256 * i;
            int row = chunk >> 4, c = chunk & 15;
            *(u16x8*)(Ps + row * 136 + c * 8) =
                *(const u16x8*)(comb + (q0 + row) * SS + s0 + c * 8);
        }
        __syncthreads();

        // S^T[s][q] = sum_d K[s][d] * Q[q][d]
        f32x4 st[8];
#pragma unroll
        for (int mt = 0; mt < 8; mt++) {
            bf16x8 a0 = *(const bf16x8*)(Ks + (mt * 16 + ln) * 72 + quad * 8);
            bf16x8 a1 = *(const bf16x8*)(Ks + (mt * 16 + ln) * 72 + 32 + quad * 8);
            f32x4 z = (f32x4){0.f, 0.f, 0.f, 0.f};
            z = __builtin_amdgcn_mfma_f32_16x16x32_bf16(a0, qf[0], z, 0, 0, 0);
            z = __builtin_amdgcn_mfma_f32_16x16x32_bf16(a1, qf[1], z, 0, 0, 0);
            st[mt] = z;
        }

        // bias frags first (aliases with P^T writes below — same addresses)
        u16x4 bfr[8];
#pragma unroll
        for (int mt = 0; mt < 8; mt++)
            bfr[mt] = *(const u16x4*)(Ps + (wave * 16 + ln) * 136 + mt * 16 + quad * 4);

        // exp, accumulate column-sum partial, write P^T[q][s]
#pragma unroll
        for (int mt = 0; mt < 8; mt++) {
            u16x4 p;
#pragma unroll
            for (int r = 0; r < 4; r++) {
                float sc = st[mt][r] + bf2f(bfr[mt][r]);
                float e = __expf(sc);
                lsum += e;
                p[r] = f2bf(e);
            }
            *(u16x4*)(Ps + (wave * 16 + ln) * 136 + mt * 16 + quad * 4) = p;
        }

        // O^T[d][q] += sum_s V^T[d][s] * P[s][q]
#pragma unroll
        for (int ks = 0; ks < 4; ks++) {
            bf16x8 pf = *(const bf16x8*)(Ps + (wave * 16 + ln) * 136 + ks * 32 + quad * 8);
#pragma unroll
            for (int mt = 0; mt < 4; mt++) {
                bf16x8 a = *(const bf16x8*)(Vs + (mt * 16 + ln) * 136 + ks * 32 + quad * 8);
                o[mt] = __builtin_amdgcn_mfma_f32_16x16x32_bf16(a, pf, o[mt], 0, 0, 0);
            }
        }
    }

    // full column sum across the 4 quads
    lsum += __shfl_xor(lsum, 16);
    lsum += __shfl_xor(lsum, 32);
    float inv = 1.f / lsum;

    // O^T -> LDS (wave-private rows, same stride as in-loop use) -> coalesced store
#pragma unroll
    for (int mt = 0; mt < 4; mt++) {
        u16x4 p;
#pragma unroll
        for (int r = 0; r < 4; r++) p[r] = f2bf(o[mt][r] * inv);
        *(u16x4*)(Ps + (wave * 16 + ln) * 136 + mt * 16 + quad * 4) = p;
    }
#pragma unroll
    for (int i = 0; i < 2; i++) {
        int qi = (lane >> 3) + i * 8;              // 0..15
        int c = lane & 7;
        u16x8 v = *(const u16x8*)(Ps + (wave * 16 + qi) * 136 + c * 8);
        *(u16x8*)(attn + (b * LL + q0 + wave * 16 + qi) * EE + h * 64 + c * 8) = v;
    }
}

// ---------------------------------------------------------------------------
extern "C" void kernel_launch(void* const* d_in, const int* in_sizes, int n_in,
                              void* d_out, int out_size, void* d_ws, size_t ws_size,
                              hipStream_t stream)
{
    (void)in_sizes; (void)n_in; (void)out_size; (void)ws_size;
    const float* query     = (const float*)d_in[0];
    const float* key       = (const float*)d_in[1];
    const float* value     = (const float*)d_in[2];
    const float* attn_bias = (const float*)d_in[3];
    const float* attn_mask = (const float*)d_in[4];
    const float* Wqkv      = (const float*)d_in[5];
    const float* bqkv      = (const float*)d_in[6];
    const float* Wo        = (const float*)d_in[7];
    const float* bo        = (const float*)d_in[8];
    float* out = (float*)d_out;

    // workspace layout (total ~92.3 MB)
    u16* q_bf   = (u16*)d_ws;
    u16* k_bf   = q_bf + MM * EE;
    u16* v_bf   = k_bf + MM * EE;
    u16* vtr    = v_bf + MM * EE;
    u16* attn   = vtr  + MM * EE;
    u16* comb   = attn + MM * EE;          // LL*SS bf16

    combine_bias_kernel<<<(LL * SS) / 2048, 256, 0, stream>>>(attn_bias, attn_mask, comb);

    dim3 gg(MM / 128, EE / 128);
    gemm_bt<0, 1><<<gg, 256, 0, stream>>>(query, Wqkv,            bqkv,        q_bf, MM, EE, EE, 0.125f);
    gemm_bt<0, 1><<<gg, 256, 0, stream>>>(key,   Wqkv + EE * EE,  bqkv + EE,   k_bf, MM, EE, EE, 1.f);
    gemm_bt<0, 1><<<gg, 256, 0, stream>>>(value, Wqkv + 2*EE*EE,  bqkv + 2*EE, v_bf, MM, EE, EE, 1.f);

    transpose_v_kernel<<<dim3(SS / 64, BB * HH), 256, 0, stream>>>(v_bf, vtr);

    attn_kernel<<<dim3(LL / 64, BB * HH), 256, 0, stream>>>(q_bf, k_bf, vtr, comb, attn);

    gemm_bt<1, 0><<<gg, 256, 0, stream>>>(attn, Wo, bo, out, MM, EE, EE, 1.f);
}

// Round 2
// 443.063 us; speedup vs baseline: 1.9375x; 1.9375x over previous
//
#include <hip/hip_runtime.h>
#include <hip/hip_bf16.h>

// Problem constants
#define BB 4
#define LL 2048
#define SS 2048
#define EE 1024
#define HH 16
#define DD 64
#define MM (BB * LL)   // 8192 rows for all projections

typedef unsigned short u16;
typedef u16   u16x4  __attribute__((ext_vector_type(4)));
typedef u16   u16x8  __attribute__((ext_vector_type(8)));
typedef float f32x4  __attribute__((ext_vector_type(4)));
typedef __bf16 bf16x8 __attribute__((ext_vector_type(8)));

__device__ __forceinline__ u16 f2bf(float x) {
    unsigned u = __float_as_uint(x);
    u += 0x7fffu + ((u >> 16) & 1u);       // RNE (inputs finite)
    return (u16)(u >> 16);
}
__device__ __forceinline__ float bf2f(u16 b) {
    return __uint_as_float(((unsigned)b) << 16);
}

// ---------------------------------------------------------------------------
// Generic fp32 -> bf16 cast, 8 elems/thread
__global__ __launch_bounds__(256) void f32_to_bf16_kernel(
    const float* __restrict__ in, u16* __restrict__ out)
{
    size_t idx = ((size_t)blockIdx.x * 256 + threadIdx.x) * 8;
    f32x4 a = *(const f32x4*)(in + idx);
    f32x4 b = *(const f32x4*)(in + idx + 4);
    u16x8 o;
#pragma unroll
    for (int j = 0; j < 4; j++) { o[j] = f2bf(a[j]); o[4 + j] = f2bf(b[j]); }
    *(u16x8*)(out + idx) = o;
}

// ---------------------------------------------------------------------------
// comb[l][s] = bf16(attn_bias[l][s] + attn_mask[l][s])
__global__ __launch_bounds__(256) void combine_bias_kernel(
    const float* __restrict__ bias, const float* __restrict__ mask,
    u16* __restrict__ comb)
{
    int idx = (blockIdx.x * 256 + threadIdx.x) * 8;
    f32x4 a0 = *(const f32x4*)(bias + idx);
    f32x4 a1 = *(const f32x4*)(bias + idx + 4);
    f32x4 m0 = *(const f32x4*)(mask + idx);
    f32x4 m1 = *(const f32x4*)(mask + idx + 4);
    u16x8 o;
#pragma unroll
    for (int j = 0; j < 4; j++) { o[j] = f2bf(a0[j] + m0[j]); o[4 + j] = f2bf(a1[j] + m1[j]); }
    *(u16x8*)(comb + idx) = o;
}

// ---------------------------------------------------------------------------
// C[m][n] = (sum_k A[m][k]*Bw[n][k] + bias[n]) * scale
// A: [M,K] fp32 (ABF16=0) or bf16 (ABF16=1); Bw: [N,K] bf16; C bf16/fp32.
// 128x128 tile, BK=64, 256 threads (4 waves 2x2), register-prefetch pipeline.
template <int ABF16, int OUTBF16>
__global__ __launch_bounds__(256, 2) void gemm_bt(
    const void* __restrict__ Ap, const u16* __restrict__ Bw,
    const float* __restrict__ bias, void* __restrict__ Cp,
    int M, int N, int K, float scale)
{
    __shared__ __align__(16) u16 As[128 * 72];
    __shared__ __align__(16) u16 Bs[128 * 72];
    const int tid = threadIdx.x;
    const int lane = tid & 63, wave = tid >> 6;
    const int quad = lane >> 4, ln = lane & 15;
    const int wm = (wave & 1) * 64, wn = (wave >> 1) * 64;
    const int m0 = blockIdx.x * 128, n0 = blockIdx.y * 128;

    f32x4 acc[4][4];
#pragma unroll
    for (int mt = 0; mt < 4; mt++)
#pragma unroll
        for (int nt = 0; nt < 4; nt++) acc[mt][nt] = (f32x4){0.f, 0.f, 0.f, 0.f};

    const float* Af = (const float*)Ap;
    const u16*   Ab = (const u16*)Ap;

    f32x4 apf[8];   // A prefetch (fp32 path)
    u16x8 apb[4];   // A prefetch (bf16 path)
    u16x8 bpf[4];   // B prefetch (bf16)

    auto load_tiles = [&](int k0) {
        if (ABF16) {
#pragma unroll
            for (int i = 0; i < 4; i++) {
                int chunk = tid + 256 * i, row = chunk >> 3, c = chunk & 7;
                apb[i] = *(const u16x8*)(Ab + (size_t)(m0 + row) * K + k0 + c * 8);
            }
        } else {
#pragma unroll
            for (int i = 0; i < 8; i++) {
                int chunk = tid + 256 * i, row = chunk >> 4, c = chunk & 15;
                apf[i] = *(const f32x4*)(Af + (size_t)(m0 + row) * K + k0 + c * 4);
            }
        }
#pragma unroll
        for (int i = 0; i < 4; i++) {
            int chunk = tid + 256 * i, row = chunk >> 3, c = chunk & 7;
            bpf[i] = *(const u16x8*)(Bw + (size_t)(n0 + row) * K + k0 + c * 8);
        }
    };

    load_tiles(0);

    for (int k0 = 0; k0 < K; k0 += 64) {
        __syncthreads();                          // prev compute's LDS reads done
        if (ABF16) {
#pragma unroll
            for (int i = 0; i < 4; i++) {
                int chunk = tid + 256 * i, row = chunk >> 3, c = chunk & 7;
                *(u16x8*)(As + row * 72 + c * 8) = apb[i];
            }
        } else {
#pragma unroll
            for (int i = 0; i < 8; i++) {
                int chunk = tid + 256 * i, row = chunk >> 4, c = chunk & 15;
                u16x4 o;
#pragma unroll
                for (int j = 0; j < 4; j++) o[j] = f2bf(apf[i][j]);
                *(u16x4*)(As + row * 72 + c * 4) = o;
            }
        }
#pragma unroll
        for (int i = 0; i < 4; i++) {
            int chunk = tid + 256 * i, row = chunk >> 3, c = chunk & 7;
            *(u16x8*)(Bs + row * 72 + c * 8) = bpf[i];
        }
        __syncthreads();

        if (k0 + 64 < K) load_tiles(k0 + 64);     // prefetch next tile into regs

#pragma unroll
        for (int ks = 0; ks < 2; ks++) {
            bf16x8 af[4], bfg[4];
#pragma unroll
            for (int mt = 0; mt < 4; mt++)
                af[mt] = *(const bf16x8*)(As + (wm + mt * 16 + ln) * 72 + ks * 32 + quad * 8);
#pragma unroll
            for (int nt = 0; nt < 4; nt++)
                bfg[nt] = *(const bf16x8*)(Bs + (wn + nt * 16 + ln) * 72 + ks * 32 + quad * 8);
#pragma unroll
            for (int mt = 0; mt < 4; mt++)
#pragma unroll
                for (int nt = 0; nt < 4; nt++)
                    acc[mt][nt] = __builtin_amdgcn_mfma_f32_16x16x32_bf16(
                        af[mt], bfg[nt], acc[mt][nt], 0, 0, 0);
        }
    }

#pragma unroll
    for (int nt = 0; nt < 4; nt++) {
        int n = n0 + wn + nt * 16 + ln;
        float bn = bias[n];
#pragma unroll
        for (int mt = 0; mt < 4; mt++) {
#pragma unroll
            for (int r = 0; r < 4; r++) {
                int m = m0 + wm + mt * 16 + quad * 4 + r;
                float val = (acc[mt][nt][r] + bn) * scale;
                if (OUTBF16) ((u16*)Cp)[(size_t)m * N + n] = f2bf(val);
                else         ((float*)Cp)[(size_t)m * N + n] = val;
            }
        }
    }
}

// ---------------------------------------------------------------------------
// vt[b][h][d][s] = v_bf[b][s][h*64+d]
__global__ __launch_bounds__(256) void transpose_v_kernel(
    const u16* __restrict__ vb, u16* __restrict__ vt)
{
    __shared__ __align__(16) u16 t[64 * 72];
    const int bh = blockIdx.y, b = bh >> 4, h = bh & 15;
    const int s0 = blockIdx.x * 64;
    const int tid = threadIdx.x;
#pragma unroll
    for (int i = 0; i < 2; i++) {
        int chunk = tid + 256 * i;                    // 512 = 64 rows x 8
        int row = chunk >> 3, c = chunk & 7;
        u16x8 v = *(const u16x8*)(vb + (size_t)(b * SS + s0 + row) * EE + h * 64 + c * 8);
        *(u16x8*)(t + row * 72 + c * 8) = v;
    }
    __syncthreads();
#pragma unroll
    for (int i = 0; i < 2; i++) {
        int chunk = tid + 256 * i;
        int d = chunk >> 3, c = chunk & 7;
        u16x8 o;
#pragma unroll
        for (int j = 0; j < 8; j++) o[j] = t[(c * 8 + j) * 72 + d];
        *(u16x8*)(vt + (size_t)(bh * 64 + d) * SS + s0 + c * 8) = o;
    }
}

// ---------------------------------------------------------------------------
// Attention: per block 128 q-rows of one (b,h); 4 waves, 32 q/wave.
// S^T = K*Q^T formulation; bias loaded direct from global in C-layout;
// Ks/Ps share one LDS union (K dead after QK phase); reg-prefetch of K/V.
__global__ __launch_bounds__(256, 2) void attn_kernel(
    const u16* __restrict__ qb,   // [B,L,E] bf16, pre-scaled
    const u16* __restrict__ kb,   // [B,S,E] bf16
    const u16* __restrict__ vt,   // [B*H,64,S] bf16
    const u16* __restrict__ comb, // [L,S] bf16 (mask+bias)
    u16* __restrict__ attn)       // [B,L,E] bf16
{
    __shared__ __align__(16) u16 KPs[128 * 136];  // union: K tile (stride 72) / P^T (stride 136)
    __shared__ __align__(16) u16 Vs[64 * 136];    // V^T tile [d][s]
    const int tid = threadIdx.x, lane = tid & 63, wave = tid >> 6;
    const int quad = lane >> 4, ln = lane & 15;
    const int bh = blockIdx.y, b = bh >> 4, h = bh & 15;
    const int q0 = blockIdx.x * 128;
    const int qloc0 = wave * 32;                  // wave's first local q row

    bf16x8 qf[2][2];
#pragma unroll
    for (int qg = 0; qg < 2; qg++)
#pragma unroll
        for (int ks = 0; ks < 2; ks++)
            qf[qg][ks] = *(const bf16x8*)(qb + (size_t)(b * LL + q0 + qloc0 + 16 * qg + ln) * EE
                                          + h * 64 + ks * 32 + quad * 8);

    const u16* cb0 = comb + (size_t)(q0 + qloc0 + ln) * SS + quad * 4;  // qg=0
    const u16* cb1 = cb0 + (size_t)16 * SS;                              // qg=1

    f32x4 o[4][2];
#pragma unroll
    for (int mt = 0; mt < 4; mt++) { o[mt][0] = (f32x4){0,0,0,0}; o[mt][1] = (f32x4){0,0,0,0}; }
    float lsum0 = 0.f, lsum1 = 0.f;

    u16x8 kreg[4], vreg[4];
    auto load_kv = [&](int s0) {
#pragma unroll
        for (int i = 0; i < 4; i++) {
            int chunk = tid + 256 * i, row = chunk >> 3, c = chunk & 7;   // 128 x 8
            kreg[i] = *(const u16x8*)(kb + (size_t)(b * SS + s0 + row) * EE + h * 64 + c * 8);
        }
#pragma unroll
        for (int i = 0; i < 4; i++) {
            int chunk = tid + 256 * i, row = chunk >> 4, c = chunk & 15;  // 64 x 16
            vreg[i] = *(const u16x8*)(vt + (size_t)(bh * 64 + row) * SS + s0 + c * 8);
        }
    };
    load_kv(0);

    for (int s0 = 0; s0 < SS; s0 += 128) {
        __syncthreads();                           // prev iter's P/V LDS reads done
#pragma unroll
        for (int i = 0; i < 4; i++) {              // K tile -> union (stride 72)
            int chunk = tid + 256 * i, row = chunk >> 3, c = chunk & 7;
            *(u16x8*)(KPs + row * 72 + c * 8) = kreg[i];
        }
#pragma unroll
        for (int i = 0; i < 4; i++) {              // V^T tile
            int chunk = tid + 256 * i, row = chunk >> 4, c = chunk & 15;
            *(u16x8*)(Vs + row * 136 + c * 8) = vreg[i];
        }
        __syncthreads();

        if (s0 + 128 < SS) load_kv(s0 + 128);      // prefetch next K/V into regs

        // bias in C-layout, straight from global (L2/L3-resident)
        u16x4 bfr[8][2];
#pragma unroll
        for (int mt = 0; mt < 8; mt++) {
            bfr[mt][0] = *(const u16x4*)(cb0 + s0 + mt * 16);
            bfr[mt][1] = *(const u16x4*)(cb1 + s0 + mt * 16);
        }

        // S^T[s][q] = sum_d K[s][d] * Q[q][d]
        f32x4 st[8][2];
#pragma unroll
        for (int mt = 0; mt < 8; mt++) {
            bf16x8 a0 = *(const bf16x8*)(KPs + (mt * 16 + ln) * 72 + quad * 8);
            bf16x8 a1 = *(const bf16x8*)(KPs + (mt * 16 + ln) * 72 + 32 + quad * 8);
#pragma unroll
            for (int qg = 0; qg < 2; qg++) {
                f32x4 z = (f32x4){0,0,0,0};
                z = __builtin_amdgcn_mfma_f32_16x16x32_bf16(a0, qf[qg][0], z, 0, 0, 0);
                z = __builtin_amdgcn_mfma_f32_16x16x32_bf16(a1, qf[qg][1], z, 0, 0, 0);
                st[mt][qg] = z;
            }
        }

        // exp before barrier (only regs involved); P^T write after barrier
        u16x4 p[8][2];
#pragma unroll
        for (int mt = 0; mt < 8; mt++)
#pragma unroll
            for (int qg = 0; qg < 2; qg++) {
#pragma unroll
                for (int r = 0; r < 4; r++) {
                    float e = __expf(st[mt][qg][r] + bf2f(bfr[mt][qg][r]));
                    if (qg == 0) lsum0 += e; else lsum1 += e;
                    p[mt][qg][r] = f2bf(e);
                }
            }

        __syncthreads();                           // all waves done reading K tile

#pragma unroll
        for (int mt = 0; mt < 8; mt++) {           // P^T -> union (stride 136), wave-private rows
            *(u16x4*)(KPs + (qloc0 + ln) * 136 + mt * 16 + quad * 4)      = p[mt][0];
            *(u16x4*)(KPs + (qloc0 + 16 + ln) * 136 + mt * 16 + quad * 4) = p[mt][1];
        }

        // O^T[d][q] += sum_s V^T[d][s] * P[s][q]
#pragma unroll
        for (int ks = 0; ks < 4; ks++) {
            bf16x8 pf0 = *(const bf16x8*)(KPs + (qloc0 + ln) * 136 + ks * 32 + quad * 8);
            bf16x8 pf1 = *(const bf16x8*)(KPs + (qloc0 + 16 + ln) * 136 + ks * 32 + quad * 8);
#pragma unroll
            for (int mt = 0; mt < 4; mt++) {
                bf16x8 a = *(const bf16x8*)(Vs + (mt * 16 + ln) * 136 + ks * 32 + quad * 8);
                o[mt][0] = __builtin_amdgcn_mfma_f32_16x16x32_bf16(a, pf0, o[mt][0], 0, 0, 0);
                o[mt][1] = __builtin_amdgcn_mfma_f32_16x16x32_bf16(a, pf1, o[mt][1], 0, 0, 0);
            }
        }
    }

    // softmax denominator: reduce across quads
    lsum0 += __shfl_xor(lsum0, 16); lsum0 += __shfl_xor(lsum0, 32);
    lsum1 += __shfl_xor(lsum1, 16); lsum1 += __shfl_xor(lsum1, 32);
    float inv0 = 1.f / lsum0, inv1 = 1.f / lsum1;

    // O^T -> LDS (wave-private rows) -> coalesced store
#pragma unroll
    for (int mt = 0; mt < 4; mt++) {
        u16x4 p0, p1;
#pragma unroll
        for (int r = 0; r < 4; r++) { p0[r] = f2bf(o[mt][0][r] * inv0); p1[r] = f2bf(o[mt][1][r] * inv1); }
        *(u16x4*)(KPs + (qloc0 + ln) * 136 + mt * 16 + quad * 4)      = p0;
        *(u16x4*)(KPs + (qloc0 + 16 + ln) * 136 + mt * 16 + quad * 4) = p1;
    }
#pragma unroll
    for (int i = 0; i < 4; i++) {
        int j = lane + 64 * i;                     // 256 chunks over wave's 32 rows
        int r = j >> 3, c = j & 7;
        u16x8 v = *(const u16x8*)(KPs + (qloc0 + r) * 136 + c * 8);
        *(u16x8*)(attn + (size_t)(b * LL + q0 + qloc0 + r) * EE + h * 64 + c * 8) = v;
    }
}

// ---------------------------------------------------------------------------
extern "C" void kernel_launch(void* const* d_in, const int* in_sizes, int n_in,
                              void* d_out, int out_size, void* d_ws, size_t ws_size,
                              hipStream_t stream)
{
    (void)in_sizes; (void)n_in; (void)out_size; (void)ws_size;
    const float* query     = (const float*)d_in[0];
    const float* key       = (const float*)d_in[1];
    const float* value     = (const float*)d_in[2];
    const float* attn_bias = (const float*)d_in[3];
    const float* attn_mask = (const float*)d_in[4];
    const float* Wqkv      = (const float*)d_in[5];
    const float* bqkv      = (const float*)d_in[6];
    const float* Wo        = (const float*)d_in[7];
    const float* bo        = (const float*)d_in[8];
    float* out = (float*)d_out;

    // workspace layout (~100.7 MB)
    u16* wq_bf = (u16*)d_ws;                 // 3*EE*EE
    u16* wo_bf = wq_bf + 3 * EE * EE;        // EE*EE
    u16* comb  = wo_bf + EE * EE;            // LL*SS
    u16* q_bf  = comb + (size_t)LL * SS;     // MM*EE each:
    u16* k_bf  = q_bf + (size_t)MM * EE;
    u16* v_bf  = k_bf + (size_t)MM * EE;
    u16* vtr   = v_bf + (size_t)MM * EE;
    u16* attnb = vtr  + (size_t)MM * EE;

    f32_to_bf16_kernel<<<3 * EE * EE / 2048, 256, 0, stream>>>(Wqkv, wq_bf);
    f32_to_bf16_kernel<<<EE * EE / 2048, 256, 0, stream>>>(Wo, wo_bf);
    combine_bias_kernel<<<(LL * SS) / 2048, 256, 0, stream>>>(attn_bias, attn_mask, comb);

    dim3 gg(MM / 128, EE / 128);
    gemm_bt<0, 1><<<gg, 256, 0, stream>>>(query, wq_bf,               bqkv,          q_bf, MM, EE, EE, 0.125f);
    gemm_bt<0, 1><<<gg, 256, 0, stream>>>(key,   wq_bf + EE * EE,     bqkv + EE,     k_bf, MM, EE, EE, 1.f);
    gemm_bt<0, 1><<<gg, 256, 0, stream>>>(value, wq_bf + 2 * EE * EE, bqkv + 2 * EE, v_bf, MM, EE, EE, 1.f);

    transpose_v_kernel<<<dim3(SS / 64, BB * HH), 256, 0, stream>>>(v_bf, vtr);

    attn_kernel<<<dim3(LL / 128, BB * HH), 256, 0, stream>>>(q_bf, k_bf, vtr, comb, attnb);

    gemm_bt<1, 0><<<gg, 256, 0, stream>>>(attnb, wo_bf, bo, out, MM, EE, EE, 1.f);
}